// Round 7
// baseline (1267.264 us; speedup 1.0000x reference)
//
#include <hip/hip_runtime.h>
#include <hip/hip_bf16.h>
#include <math.h>

#define B_   64
#define S_   512
#define K_   16
#define H_   256
#define H4_  1024

typedef __attribute__((ext_vector_type(4))) float f32x4;
typedef __attribute__((ext_vector_type(8))) short bf16x8;

// ---------------- helpers ----------------
__device__ __forceinline__ float wave_reduce_sum(float v) {
#pragma unroll
  for (int off = 32; off; off >>= 1) v += __shfl_down(v, off, 64);
  return v;
}
__device__ __forceinline__ float wave_reduce_max(float v) {
#pragma unroll
  for (int off = 32; off; off >>= 1) v = fmaxf(v, __shfl_down(v, off, 64));
  return v;
}
__device__ __forceinline__ float tanh_fast(float x) {
  const float e = __expf(2.f * x);
  return 1.f - __fdividef(2.f, e + 1.f);
}
__device__ __forceinline__ float sigmoid_fast(float x) {
  return __fdividef(1.f, 1.f + __expf(-x));
}
__device__ __forceinline__ ushort f2bf(float f) {   // RNE fp32->bf16
  union { float f; unsigned u; } v; v.f = f;
  unsigned r = v.u + 0x7FFFu + ((v.u >> 16) & 1u);
  return (ushort)(r >> 16);
}

// ---------------- gather: x = [embed_item[cand], embed_user[user]] (fp32 + bf16) ----------------
__global__ void gather_x(const int* __restrict__ users, const int* __restrict__ cand,
                         const float* __restrict__ eu, const float* __restrict__ ei,
                         float* __restrict__ x, ushort* __restrict__ xb)
{
  int idx = blockIdx.x * 256 + threadIdx.x;          // B*S*H = 8388608
  int h  = idx & (H_ - 1);
  int bs = idx >> 8;
  int b  = bs >> 9;
  float v;
  if (h < 192) v = ei[(long)cand[bs] * 192 + h];
  else         v = eu[(long)users[b] * 64 + (h - 192)];
  x[idx] = v;
  xb[idx] = f2bf(v);
}

// ---------------- transpose+convert weights: in fp32 [R,C] -> out bf16 [C,R] ----------------
__global__ __launch_bounds__(256) void tcvt(const float* __restrict__ in, ushort* __restrict__ out,
                                            int R, int C)
{
  __shared__ float t[32][33];
  const int c0 = blockIdx.x * 32, r0 = blockIdx.y * 32;
  const int tx = threadIdx.x & 31, ty = threadIdx.x >> 5;   // ty 0..7
#pragma unroll
  for (int i = 0; i < 4; ++i)
    t[ty + 8 * i][tx] = in[(long)(r0 + ty + 8 * i) * C + c0 + tx];
  __syncthreads();
#pragma unroll
  for (int i = 0; i < 4; ++i)
    out[(long)(c0 + ty + 8 * i) * R + r0 + tx] = f2bf(t[tx][ty + 8 * i]);
}

// ---------------- six 256x256 transposes+convert in one launch (z picks matrix) ----------------
__global__ __launch_bounds__(256) void tcvt6(
    const float* __restrict__ i0, ushort* __restrict__ o0,
    const float* __restrict__ i1, ushort* __restrict__ o1,
    const float* __restrict__ i2, ushort* __restrict__ o2,
    const float* __restrict__ i3, ushort* __restrict__ o3,
    const float* __restrict__ i4, ushort* __restrict__ o4,
    const float* __restrict__ i5, ushort* __restrict__ o5)
{
  __shared__ float t[32][33];
  const float* in; ushort* out;
  switch (blockIdx.z) {
    case 0: in = i0; out = o0; break;
    case 1: in = i1; out = o1; break;
    case 2: in = i2; out = o2; break;
    case 3: in = i3; out = o3; break;
    case 4: in = i4; out = o4; break;
    default: in = i5; out = o5; break;
  }
  const int c0 = blockIdx.x * 32, r0 = blockIdx.y * 32;
  const int tx = threadIdx.x & 31, ty = threadIdx.x >> 5;
#pragma unroll
  for (int i = 0; i < 4; ++i)
    t[ty + 8 * i][tx] = in[(long)(r0 + ty + 8 * i) * 256 + c0 + tx];
  __syncthreads();
#pragma unroll
  for (int i = 0; i < 4; ++i)
    out[(long)(c0 + ty + 8 * i) * 256 + r0 + tx] = f2bf(t[tx][ty + 8 * i]);
}

// ---------------- flat fp32 -> bf16 ----------------
__global__ void cvtflat(const float* __restrict__ in, ushort* __restrict__ out)
{
  int idx = blockIdx.x * 256 + threadIdx.x;
  out[idx] = f2bf(in[idx]);
}

// ---------------- bf16 MFMA GEMM: C = A[M,K] @ BT[N,K]^T (+bias)(+relu) ----------------
// 128x128 tile, BK=32, 4 waves (2x2), wave = 64x64 = 4x4 mfma_f32_16x16x32_bf16 frags.
// OM: 0 = fp32 out, 1 = bf16 out, 2 = fp32 batched-T out [b][h=N][s] (S=512,H=256),
//     3 = bf16 batched-T out (same layout). OM 2/3 require bz==0, rows = b*512+s.
template<int OM, bool RELU>
__global__ __launch_bounds__(256) void gemm_bf16(
    const ushort* __restrict__ A, const ushort* __restrict__ BT,
    const float* __restrict__ bias, void* __restrict__ Cv,
    int K, int ldA, int ldB, int ldC, long sA, long sB, long sC)
{
  __shared__ ushort Al[128][40];   // pad 32->40 elems (80B rows)
  __shared__ ushort Bl[128][40];
  const int bx = blockIdx.x, by = blockIdx.y, bz = blockIdx.z;
  A  += (long)bz * sA + (long)by * 128 * ldA;
  BT += (long)bz * sB + (long)bx * 128 * ldB;
  const int tid = threadIdx.x, lane = tid & 63, wave = tid >> 6;
  const int wr = wave >> 1, wc = wave & 1;
  const int fr = lane & 15, fq = lane >> 4;
  const int srow = tid & 127;
  const int scol = (tid >> 7) * 16;               // ushort offset: 0 or 16

  const f32x4 fzero = {0.f, 0.f, 0.f, 0.f};
  f32x4 acc[4][4];
#pragma unroll
  for (int i = 0; i < 4; ++i)
#pragma unroll
    for (int j = 0; j < 4; ++j) acc[i][j] = fzero;

  for (int k0 = 0; k0 < K; k0 += 32) {
    const ushort* ap = A  + (long)srow * ldA + k0 + scol;
    const ushort* bp = BT + (long)srow * ldB + k0 + scol;
    *(uint4*)&Al[srow][scol]     = *(const uint4*)(ap);
    *(uint4*)&Al[srow][scol + 8] = *(const uint4*)(ap + 8);
    *(uint4*)&Bl[srow][scol]     = *(const uint4*)(bp);
    *(uint4*)&Bl[srow][scol + 8] = *(const uint4*)(bp + 8);
    __syncthreads();
    bf16x8 af[4], bfr[4];
#pragma unroll
    for (int i = 0; i < 4; ++i) af[i]  = *(const bf16x8*)&Al[wr * 64 + i * 16 + fr][fq * 8];
#pragma unroll
    for (int j = 0; j < 4; ++j) bfr[j] = *(const bf16x8*)&Bl[wc * 64 + j * 16 + fr][fq * 8];
#pragma unroll
    for (int i = 0; i < 4; ++i)
#pragma unroll
      for (int j = 0; j < 4; ++j)
        acc[i][j] = __builtin_amdgcn_mfma_f32_16x16x32_bf16(af[i], bfr[j], acc[i][j], 0, 0, 0);
    __syncthreads();
  }

  const int rowb = by * 128 + wr * 64 + fq * 4;
  const int colb = bx * 128 + wc * 64 + fr;
#pragma unroll
  for (int j = 0; j < 4; ++j) {
    const int colg = colb + j * 16;
    const float bb = bias ? bias[colg] : 0.f;
#pragma unroll
    for (int i = 0; i < 4; ++i) {
      const int rowg = rowb + i * 16;
      if (OM == 0) {
        float* C = (float*)Cv;
#pragma unroll
        for (int r = 0; r < 4; ++r) {
          float o = acc[i][j][r] + bb;
          if (RELU) o = fmaxf(o, 0.f);
          C[(long)bz * sC + (long)(rowg + r) * ldC + colg] = o;
        }
      } else if (OM == 1) {
        ushort* C = (ushort*)Cv;
#pragma unroll
        for (int r = 0; r < 4; ++r) {
          float o = acc[i][j][r] + bb;
          if (RELU) o = fmaxf(o, 0.f);
          C[(long)bz * sC + (long)(rowg + r) * ldC + colg] = f2bf(o);
        }
      } else if (OM == 2) {
        float* C = (float*)Cv;
        const long ct = ((long)(rowg >> 9) * H_ + colg) * S_ + (rowg & 511);
        float4 o;
        o.x = acc[i][j][0] + bb; o.y = acc[i][j][1] + bb;
        o.z = acc[i][j][2] + bb; o.w = acc[i][j][3] + bb;
        *(float4*)&C[ct] = o;
      } else {
        ushort* C = (ushort*)Cv;
        const long ct = ((long)(rowg >> 9) * H_ + colg) * S_ + (rowg & 511);
        ushort4 o;
        o.x = f2bf(acc[i][j][0] + bb); o.y = f2bf(acc[i][j][1] + bb);
        o.z = f2bf(acc[i][j][2] + bb); o.w = f2bf(acc[i][j][3] + bb);
        *(ushort4*)&C[ct] = o;
      }
    }
  }
}

// ---------------- attention softmax: fp32 scores -> bf16 probs ----------------
__global__ __launch_bounds__(256) void attn_softmax(const float* __restrict__ att,
                                                    ushort* __restrict__ attb)
{
  __shared__ float red[4];
  const long row = blockIdx.x;
  const float* p = att + row * S_;
  const int t = threadIdx.x, lane = t & 63, wid = t >> 6;
  float v0 = p[t] * 0.0625f, v1 = p[t + 256] * 0.0625f;
  float m = wave_reduce_max(fmaxf(v0, v1));
  if (!lane) red[wid] = m;
  __syncthreads();
  const float bm = fmaxf(fmaxf(red[0], red[1]), fmaxf(red[2], red[3]));
  const float e0 = __expf(v0 - bm), e1 = __expf(v1 - bm);
  float s = wave_reduce_sum(e0 + e1);
  __syncthreads();
  if (!lane) red[wid] = s;
  __syncthreads();
  const float inv = __fdividef(1.f, red[0] + red[1] + red[2] + red[3]);
  ushort* q = attb + row * S_;
  q[t] = f2bf(e0 * inv); q[t + 256] = f2bf(e1 * inv);
}

// ---------------- residual + layernorm -> x (fp32) and xb (bf16) ----------------
__global__ __launch_bounds__(256) void ln_res(float* __restrict__ x, const float* __restrict__ y,
                                              const float* __restrict__ g, const float* __restrict__ b,
                                              ushort* __restrict__ xb)
{
  __shared__ float red[4];
  const long row = blockIdx.x;
  const int t = threadIdx.x, lane = t & 63, wid = t >> 6;
  float v = x[row * H_ + t] + y[row * H_ + t];
  float s = wave_reduce_sum(v);
  if (!lane) red[wid] = s;
  __syncthreads();
  const float mean = (red[0] + red[1] + red[2] + red[3]) * (1.f / H_);
  const float d = v - mean;
  float s2 = wave_reduce_sum(d * d);
  __syncthreads();
  if (!lane) red[wid] = s2;
  __syncthreads();
  const float var = (red[0] + red[1] + red[2] + red[3]) * (1.f / H_);
  const float o = d * rsqrtf(var + 1e-5f) * g[t] + b[t];
  x[row * H_ + t] = o;
  xb[row * H_ + t] = f2bf(o);
}

// ---------------- gather LSTM inputs from encb (bf16), step 0 zeroed ----------------
__global__ void gather_inputs(const int* __restrict__ tidx, const ushort* __restrict__ encb,
                              ushort* __restrict__ inpb)
{
  int idx = blockIdx.x * 256 + threadIdx.x;          // 1024*256
  int h = idx & 255, kb = idx >> 8;
  int b = kb & 63, k = kb >> 6;
  ushort v = 0;
  if (k > 0) {
    int s = tidx[b * K_ + k];
    v = encb[((long)b * S_ + s) * H_ + h];
  }
  inpb[idx] = v;
}

// ---------------- MFMA LSTM: one block per batch row, gates GEMM on matrix cores ----------------
// 4 waves; wave w owns gate cols [w*256, w*256+256). h kept as bf16 in LDS (c stays fp32).
// A-fragment = h broadcast to all 16 rows (every lane loads by its k-index) -> all C rows valid.
__global__ __launch_bounds__(256) void lstm_mfma(const float* __restrict__ Xp,
                                                 const ushort* __restrict__ Whhb,  // [1024][256] bf16
                                                 const float* __restrict__ b_hh,
                                                 float* __restrict__ dec)
{
  __shared__ ushort hsb[H_];
  __shared__ float gates[H4_];
  const int b = blockIdx.x, tid = threadIdx.x;
  const int lane = tid & 63, wave = tid >> 6;
  const int fr = lane & 15, fq = lane >> 4;
  const int n0 = wave * 256;
  if (tid < 128) ((uint*)hsb)[tid] = 0;       // h = 0
  float c = 0.f;
  const int j = tid;                          // elementwise: thread j owns h[j], c[j]
  const float bh0 = b_hh[j], bh1 = b_hh[256 + j], bh2 = b_hh[512 + j], bh3 = b_hh[768 + j];
  __syncthreads();
  for (int step = 0; step < K_; ++step) {
    // A-fragments: broadcast reads of h (identical across lanes in each 16-lane group)
    bf16x8 af[8];
#pragma unroll
    for (int kc = 0; kc < 8; ++kc)
      af[kc] = *(const bf16x8*)&hsb[kc * 32 + fq * 8];
    // 16 n-tiles of 16 gate-cols each; W fragments streamed from L2 (dwordx4)
#pragma unroll 4
    for (int nt = 0; nt < 16; ++nt) {
      const ushort* wp = Whhb + (long)(n0 + nt * 16 + fr) * 256 + fq * 8;
      f32x4 acc = {0.f, 0.f, 0.f, 0.f};
#pragma unroll
      for (int kc = 0; kc < 8; ++kc) {
        const bf16x8 bf = *(const bf16x8*)(wp + kc * 32);
        acc = __builtin_amdgcn_mfma_f32_16x16x32_bf16(af[kc], bf, acc, 0, 0, 0);
      }
      if (lane < 16) gates[n0 + nt * 16 + lane] = acc[0];   // row 0 copy
    }
    __syncthreads();
    // elementwise gate update
    {
      const long xrow = ((long)step * B_ + b) * H4_ + j;
      const float gi = gates[j]       + Xp[xrow]       + bh0;
      const float gf = gates[256 + j] + Xp[xrow + 256] + bh1;
      const float gg = gates[512 + j] + Xp[xrow + 512] + bh2;
      const float go = gates[768 + j] + Xp[xrow + 768] + bh3;
      c = sigmoid_fast(gf) * c + sigmoid_fast(gi) * tanh_fast(gg);
      const float h = sigmoid_fast(go) * tanh_fast(c);
      const long rw = ((long)step * B_ + b) * (2 * H_);
      dec[rw + j] = h;
      dec[rw + H_ + j] = c;
      hsb[j] = f2bf(h);
    }
    __syncthreads();
  }
}

// ---------------- glimpse: per-lane-s scores, softmax, weighted sum ----------------
__global__ __launch_bounds__(256) void glimpse_kernel(
    const float* __restrict__ decW1, const float* __restrict__ encW2T,
    const float* __restrict__ enc, const float* __restrict__ bias1,
    const float* __restrict__ V1, float* __restrict__ glim)
{
  __shared__ float dv[H_], vd[H_], sc[S_], red[4];
  const int bid = blockIdx.x;                // k*B + b
  const int b = bid & 63;
  const int t = threadIdx.x, lane = t & 63, wv = t >> 6;
  dv[t] = decW1[(long)bid * H_ + t] + bias1[t];
  vd[t] = V1[t];
  __syncthreads();
  const float* ebase = encW2T + (long)b * H_ * S_;
  float a0 = 0.f, a1 = 0.f;
#pragma unroll 4
  for (int h = 0; h < H_; ++h) {
    const float d = dv[h], w = vd[h];
    const float* r = ebase + (long)h * S_;
    a0 += tanh_fast(d + r[t]) * w;
    a1 += tanh_fast(d + r[t + 256]) * w;
  }
  float m = wave_reduce_max(fmaxf(a0, a1));
  if (!lane) red[wv] = m;
  __syncthreads();
  const float bm = fmaxf(fmaxf(red[0], red[1]), fmaxf(red[2], red[3]));
  const float e0 = __expf(a0 - bm), e1 = __expf(a1 - bm);
  float ssum = wave_reduce_sum(e0 + e1);
  __syncthreads();
  if (!lane) red[wv] = ssum;
  __syncthreads();
  const float inv = __fdividef(1.f, red[0] + red[1] + red[2] + red[3]);
  sc[t] = e0 * inv; sc[t + 256] = e1 * inv;
  __syncthreads();
  float acc = 0.f;
  const float* eb = enc + (long)b * S_ * H_ + t;
#pragma unroll 4
  for (int s = 0; s < S_; ++s) acc += sc[s] * eb[(long)s * H_];
  glim[(long)bid * H_ + t] = acc;
}

// ---------------- gcat = [dec | glim] -> bf16 ----------------
__global__ void concat_gcat(const float* __restrict__ dec, const float* __restrict__ glim,
                            ushort* __restrict__ gcatb)
{
  int idx = blockIdx.x * 256 + threadIdx.x;   // 1024*768
  int j = idx % 768, row = idx / 768;
  float v = (j < 512) ? dec[(long)row * 512 + j] : glim[(long)row * 256 + (j - 512)];
  gcatb[idx] = f2bf(v);
}

// ---------------- pointer logits -> out[b,k,s] ----------------
__global__ __launch_bounds__(256) void pointer_kernel(
    const float* __restrict__ gW3, const float* __restrict__ encW4T,
    const float* __restrict__ bias2, const float* __restrict__ V2,
    float* __restrict__ out)
{
  __shared__ float dv[H_], vd[H_];
  const int bid = blockIdx.x;                // k*B + b
  const int b = bid & 63, k = bid >> 6;
  const int t = threadIdx.x;
  dv[t] = gW3[(long)bid * H_ + t] + bias2[t];
  vd[t] = V2[t];
  __syncthreads();
  const float* ebase = encW4T + (long)b * H_ * S_;
  float a0 = 0.f, a1 = 0.f;
#pragma unroll 4
  for (int h = 0; h < H_; ++h) {
    const float d = dv[h], w = vd[h];
    const float* r = ebase + (long)h * S_;
    a0 += tanh_fast(d + r[t]) * w;
    a1 += tanh_fast(d + r[t + 256]) * w;
  }
  const long ro = ((long)b * K_ + k) * S_;
  out[ro + t] = a0;
  out[ro + 256 + t] = a1;
}

// ---------------- host ----------------
extern "C" void kernel_launch(void* const* d_in, const int* in_sizes, int n_in,
                              void* d_out, int out_size, void* d_ws, size_t ws_size,
                              hipStream_t stream)
{
  const int*   users = (const int*)d_in[0];
  const int*   cand  = (const int*)d_in[1];
  const int*   tidx  = (const int*)d_in[2];
  const float* eu    = (const float*)d_in[3];
  const float* ei    = (const float*)d_in[4];
  const float* Wq    = (const float*)d_in[5];
  const float* bq    = (const float*)d_in[6];
  const float* Wk    = (const float*)d_in[7];
  const float* bk    = (const float*)d_in[8];
  const float* Wv    = (const float*)d_in[9];
  const float* bv    = (const float*)d_in[10];
  const float* Wo    = (const float*)d_in[11];
  const float* bo    = (const float*)d_in[12];
  const float* ln1g  = (const float*)d_in[13];
  const float* ln1b  = (const float*)d_in[14];
  const float* Wf1   = (const float*)d_in[15];
  const float* bf1   = (const float*)d_in[16];
  const float* Wf2   = (const float*)d_in[17];
  const float* bf2   = (const float*)d_in[18];
  const float* ln2g  = (const float*)d_in[19];
  const float* ln2b  = (const float*)d_in[20];
  const float* W_ih  = (const float*)d_in[21];
  const float* W_hh  = (const float*)d_in[22];
  const float* b_ih  = (const float*)d_in[23];
  const float* b_hh  = (const float*)d_in[24];
  const float* W_D1  = (const float*)d_in[25];
  const float* W_D2  = (const float*)d_in[26];
  const float* bias1 = (const float*)d_in[27];
  const float* V_D1  = (const float*)d_in[28];
  const float* W_D3  = (const float*)d_in[29];
  const float* W_D4  = (const float*)d_in[30];
  const float* bias2 = (const float*)d_in[31];
  const float* V_D2  = (const float*)d_in[32];

  float* ws = (float*)d_ws;
  // arena (float-element offsets)
  float*  x      = ws;                               // fp32 8388608 (x -> enc)
  ushort* xb     = (ushort*)(ws + 8388608);          // bf16 (xb -> encb)
  ushort* qb     = (ushort*)(ws + 12582912);
  ushort* kb     = (ushort*)(ws + 16777216);
  ushort* vTb    = (ushort*)(ws + 20971520);         // [b][h][s] bf16
  ushort* aob    = (ushort*)(ws + 25165824);
  ushort* attb   = (ushort*)(ws + 29360128);         // 16x512x512 bf16 chunk
  float*  ych    = ws + 31457280;                    // 8192x256 fp32 chunk
  ushort* wts    = (ushort*)(ws + 33554432);         // bf16 weights arena
  float*  att    = ws + 34603008;                    // 16x512x512 fp32 chunk
  ushort* midb   = (ushort*)att;                     // alias: FFN phase (att dead)
  float*  sm     = ws + 38797312;                    // small arena
  float*  encW2T = ws + 12582912;                    // overlays qb+kb (dead)
  float*  encW4T = ws + 20971520;                    // overlays vTb+aob (dead)

  ushort* WqT  = wts;
  ushort* WkT  = WqT  + 65536;
  ushort* WvT  = WkT  + 65536;
  ushort* WoT  = WvT  + 65536;
  ushort* Wf1T = WoT  + 65536;
  ushort* Wf2T = Wf1T + 262144;
  ushort* WD1T = Wf2T + 262144;
  ushort* WD2T = WD1T + 131072;
  ushort* WD3T = WD2T + 65536;
  ushort* WD4T = WD3T + 196608;
  ushort* Wihb = WD4T + 65536;

  ushort* inpb   = (ushort*)sm;                      // 1024x256 bf16
  float*  Xp     = sm + 131072;                      // 1024x1024 fp32
  ushort* Whhb   = (ushort*)(sm + 1179648);          // 1024x256 bf16
  float*  dec    = sm + 1441792;                     // 16x64x512 fp32
  ushort* decb   = (ushort*)(sm + 1966080);
  float*  decW1  = sm + 2228224;
  float*  glim   = sm + 2490368;
  ushort* gcatb  = (ushort*)(sm + 2752512);          // 1024x768 bf16
  float*  gcatW3 = sm + 3145728;

  float* out = (float*)d_out;
  const long SH = (long)S_ * H_;                     // 131072

  // 0. weight prep (transpose + cvt to bf16 [N,K])
  tcvt6<<<dim3(8,8,6), dim3(256), 0, stream>>>(Wq, WqT, Wk, WkT, Wv, WvT,
                                               Wo, WoT, W_D2, WD2T, W_D4, WD4T);
  tcvt<<<dim3(32,8),  dim3(256), 0, stream>>>(Wf1,  Wf1T, 256, 1024);
  tcvt<<<dim3(8,32),  dim3(256), 0, stream>>>(Wf2,  Wf2T, 1024, 256);
  tcvt<<<dim3(8,16),  dim3(256), 0, stream>>>(W_D1, WD1T, 512, 256);
  tcvt<<<dim3(8,24),  dim3(256), 0, stream>>>(W_D3, WD3T, 768, 256);
  cvtflat<<<dim3(1024), dim3(256), 0, stream>>>(W_ih, Wihb);   // already [N,K]
  cvtflat<<<dim3(1024), dim3(256), 0, stream>>>(W_hh, Whhb);   // already [N,K]

  // 1. gather
  gather_x<<<dim3(32768), dim3(256), 0, stream>>>(users, cand, eu, ei, x, xb);

  // 2. q,k (bf16 out), v (bf16 transposed out)
  gemm_bf16<1,false><<<dim3(2,256), dim3(256), 0, stream>>>(xb, WqT, bq, qb,  256, 256, 256, 256, 0,0,0);
  gemm_bf16<1,false><<<dim3(2,256), dim3(256), 0, stream>>>(xb, WkT, bk, kb,  256, 256, 256, 256, 0,0,0);
  gemm_bf16<3,false><<<dim3(2,256), dim3(256), 0, stream>>>(xb, WvT, bv, vTb, 256, 256, 256, 0,   0,0,0);

  // 3. attention: 4 chunks of 16 batches
  for (int c = 0; c < 4; ++c) {
    const long qo = (long)c * 16 * SH;
    gemm_bf16<0,false><<<dim3(4,4,16), dim3(256), 0, stream>>>(
        qb + qo, kb + qo, nullptr, att, 256, 256, 256, 512, SH, SH, (long)S_*S_);
    attn_softmax<<<dim3(16*S_), dim3(256), 0, stream>>>(att, attb);
    gemm_bf16<1,false><<<dim3(2,4,16), dim3(256), 0, stream>>>(
        attb, vTb + qo, nullptr, aob + qo, 512, 512, 512, 256, (long)S_*S_, SH, SH);
  }

  // 4. Wo + LN1, 4 row-chunks of 8192
  for (int c = 0; c < 4; ++c) {
    const long off = (long)c * 8192 * H_;
    gemm_bf16<0,false><<<dim3(2,64), dim3(256), 0, stream>>>(aob + off, WoT, bo, ych, 256, 256, 256, 256, 0,0,0);
    ln_res<<<dim3(8192), dim3(256), 0, stream>>>(x + off, ych, ln1g, ln1b, xb + off);
  }

  // 5. FFN, 4 row-chunks of 8192 (mid bf16 in att slot)
  for (int c = 0; c < 4; ++c) {
    const long off = (long)c * 8192 * H_;
    gemm_bf16<1,true ><<<dim3(8,64), dim3(256), 0, stream>>>(xb + off, Wf1T, bf1, midb, 256, 256, 256, 1024, 0,0,0);
    gemm_bf16<0,false><<<dim3(2,64), dim3(256), 0, stream>>>(midb, Wf2T, bf2, ych, 1024, 1024, 1024, 256, 0,0,0);
    ln_res<<<dim3(8192), dim3(256), 0, stream>>>(x + off, ych, ln2g, ln2b, xb + off);
  }
  // x = enc (fp32), xb = encb (bf16)

  // 6. enc projections, emitted pre-transposed [b][h][s] fp32
  gemm_bf16<2,false><<<dim3(2,256), dim3(256), 0, stream>>>(xb, WD2T, nullptr, encW2T, 256, 256, 256, 0, 0,0,0);
  gemm_bf16<2,false><<<dim3(2,256), dim3(256), 0, stream>>>(xb, WD4T, nullptr, encW4T, 256, 256, 256, 0, 0,0,0);

  // 7. LSTM
  gather_inputs<<<dim3(1024), dim3(256), 0, stream>>>(tidx, xb, inpb);
  gemm_bf16<0,false><<<dim3(8,8), dim3(256), 0, stream>>>(inpb, Wihb, b_ih, Xp, 256, 256, 256, 1024, 0,0,0);
  lstm_mfma<<<dim3(B_), dim3(256), 0, stream>>>(Xp, Whhb, b_hh, dec);

  // 8. glimpse
  cvtflat<<<dim3(2048), dim3(256), 0, stream>>>(dec, decb);
  gemm_bf16<0,false><<<dim3(2,8), dim3(256), 0, stream>>>(decb, WD1T, nullptr, decW1, 512, 512, 512, 256, 0,0,0);
  glimpse_kernel<<<dim3(K_*B_), dim3(256), 0, stream>>>(decW1, encW2T, x, bias1, V_D1, glim);

  // 9. pointer
  concat_gcat<<<dim3(3072), dim3(256), 0, stream>>>(dec, glim, gcatb);
  gemm_bf16<0,false><<<dim3(2,8), dim3(256), 0, stream>>>(gcatb, WD3T, nullptr, gcatW3, 768, 768, 768, 256, 0,0,0);
  pointer_kernel<<<dim3(K_*B_), dim3(256), 0, stream>>>(gcatW3, encW4T, bias2, V_D2, out);
}

// Round 12
// 1103.275 us; speedup vs baseline: 1.1486x; 1.1486x over previous
//
#include <hip/hip_runtime.h>
#include <hip/hip_bf16.h>
#include <math.h>

#define B_   64
#define S_   512
#define K_   16
#define H_   256
#define H4_  1024

typedef __attribute__((ext_vector_type(4))) float f32x4;
typedef __attribute__((ext_vector_type(8))) short bf16x8;

// ---------------- helpers ----------------
__device__ __forceinline__ float wave_reduce_sum(float v) {
#pragma unroll
  for (int off = 32; off; off >>= 1) v += __shfl_down(v, off, 64);
  return v;
}
__device__ __forceinline__ float wave_reduce_max(float v) {
#pragma unroll
  for (int off = 32; off; off >>= 1) v = fmaxf(v, __shfl_down(v, off, 64));
  return v;
}
__device__ __forceinline__ float tanh_fast(float x) {
  const float e = __expf(2.f * x);
  return 1.f - __fdividef(2.f, e + 1.f);
}
__device__ __forceinline__ float sigmoid_fast(float x) {
  return __fdividef(1.f, 1.f + __expf(-x));
}
__device__ __forceinline__ ushort f2bf(float f) {   // RNE fp32->bf16
  union { float f; unsigned u; } v; v.f = f;
  unsigned r = v.u + 0x7FFFu + ((v.u >> 16) & 1u);
  return (ushort)(r >> 16);
}

// ---------------- gather: x = [embed_item[cand], embed_user[user]] (fp32 + bf16) ----------------
__global__ void gather_x(const int* __restrict__ users, const int* __restrict__ cand,
                         const float* __restrict__ eu, const float* __restrict__ ei,
                         float* __restrict__ x, ushort* __restrict__ xb)
{
  int idx = blockIdx.x * 256 + threadIdx.x;          // B*S*H = 8388608
  int h  = idx & (H_ - 1);
  int bs = idx >> 8;
  int b  = bs >> 9;
  float v;
  if (h < 192) v = ei[(long)cand[bs] * 192 + h];
  else         v = eu[(long)users[b] * 64 + (h - 192)];
  x[idx] = v;
  xb[idx] = f2bf(v);
}

// ---------------- transpose+convert weights: in fp32 [R,C] -> out bf16 [C,R] ----------------
__global__ __launch_bounds__(256) void tcvt(const float* __restrict__ in, ushort* __restrict__ out,
                                            int R, int C)
{
  __shared__ float t[32][33];
  const int c0 = blockIdx.x * 32, r0 = blockIdx.y * 32;
  const int tx = threadIdx.x & 31, ty = threadIdx.x >> 5;   // ty 0..7
#pragma unroll
  for (int i = 0; i < 4; ++i)
    t[ty + 8 * i][tx] = in[(long)(r0 + ty + 8 * i) * C + c0 + tx];
  __syncthreads();
#pragma unroll
  for (int i = 0; i < 4; ++i)
    out[(long)(c0 + ty + 8 * i) * R + r0 + tx] = f2bf(t[tx][ty + 8 * i]);
}

// ---------------- six 256x256 transposes+convert in one launch (z picks matrix) ----------------
__global__ __launch_bounds__(256) void tcvt6(
    const float* __restrict__ i0, ushort* __restrict__ o0,
    const float* __restrict__ i1, ushort* __restrict__ o1,
    const float* __restrict__ i2, ushort* __restrict__ o2,
    const float* __restrict__ i3, ushort* __restrict__ o3,
    const float* __restrict__ i4, ushort* __restrict__ o4,
    const float* __restrict__ i5, ushort* __restrict__ o5)
{
  __shared__ float t[32][33];
  const float* in; ushort* out;
  switch (blockIdx.z) {
    case 0: in = i0; out = o0; break;
    case 1: in = i1; out = o1; break;
    case 2: in = i2; out = o2; break;
    case 3: in = i3; out = o3; break;
    case 4: in = i4; out = o4; break;
    default: in = i5; out = o5; break;
  }
  const int c0 = blockIdx.x * 32, r0 = blockIdx.y * 32;
  const int tx = threadIdx.x & 31, ty = threadIdx.x >> 5;
#pragma unroll
  for (int i = 0; i < 4; ++i)
    t[ty + 8 * i][tx] = in[(long)(r0 + ty + 8 * i) * 256 + c0 + tx];
  __syncthreads();
#pragma unroll
  for (int i = 0; i < 4; ++i)
    out[(long)(c0 + ty + 8 * i) * 256 + r0 + tx] = f2bf(t[tx][ty + 8 * i]);
}

// ---------------- flat fp32 -> bf16 ----------------
__global__ void cvtflat(const float* __restrict__ in, ushort* __restrict__ out)
{
  int idx = blockIdx.x * 256 + threadIdx.x;
  out[idx] = f2bf(in[idx]);
}

// ---------------- W_hh -> MFMA-B-fragment-ordered bf16 copy ----------------
// Wp[((ntg*8 + kc)*64 + lane)*8 + i] = W_hh[n][k], n = ntg*16 + (lane&15),
// k = kc*32 + ((lane>>4))*8 + i.  A wave's fragment load = contiguous 1KB.
__global__ void whh_prep(const float* __restrict__ W, ushort* __restrict__ Wp)
{
  int idx = blockIdx.x * 256 + threadIdx.x;          // 262144
  const int i    = idx & 7;
  const int lane = (idx >> 3) & 63;
  const int kc   = (idx >> 9) & 7;
  const int ntg  = idx >> 12;
  const int n = ntg * 16 + (lane & 15);
  const int k = kc * 32 + (lane >> 4) * 8 + i;
  Wp[idx] = f2bf(W[n * 256 + k]);
}

// ---------------- bf16 MFMA GEMM: C = A[M,K] @ BT[N,K]^T (+bias)(+relu) ----------------
// 128x128 tile, BK=32, 4 waves (2x2), wave = 64x64 = 4x4 mfma_f32_16x16x32_bf16 frags.
// OM: 0 = fp32 out, 1 = bf16 out, 2 = fp32 batched-T out [b][h=N][s] (S=512,H=256),
//     3 = bf16 batched-T out (same layout). OM 2/3 require bz==0, rows = b*512+s.
template<int OM, bool RELU>
__global__ __launch_bounds__(256) void gemm_bf16(
    const ushort* __restrict__ A, const ushort* __restrict__ BT,
    const float* __restrict__ bias, void* __restrict__ Cv,
    int K, int ldA, int ldB, int ldC, long sA, long sB, long sC)
{
  __shared__ ushort Al[128][40];   // pad 32->40 elems (80B rows)
  __shared__ ushort Bl[128][40];
  const int bx = blockIdx.x, by = blockIdx.y, bz = blockIdx.z;
  A  += (long)bz * sA + (long)by * 128 * ldA;
  BT += (long)bz * sB + (long)bx * 128 * ldB;
  const int tid = threadIdx.x, lane = tid & 63, wave = tid >> 6;
  const int wr = wave >> 1, wc = wave & 1;
  const int fr = lane & 15, fq = lane >> 4;
  const int srow = tid & 127;
  const int scol = (tid >> 7) * 16;               // ushort offset: 0 or 16

  const f32x4 fzero = {0.f, 0.f, 0.f, 0.f};
  f32x4 acc[4][4];
#pragma unroll
  for (int i = 0; i < 4; ++i)
#pragma unroll
    for (int j = 0; j < 4; ++j) acc[i][j] = fzero;

  for (int k0 = 0; k0 < K; k0 += 32) {
    const ushort* ap = A  + (long)srow * ldA + k0 + scol;
    const ushort* bp = BT + (long)srow * ldB + k0 + scol;
    *(uint4*)&Al[srow][scol]     = *(const uint4*)(ap);
    *(uint4*)&Al[srow][scol + 8] = *(const uint4*)(ap + 8);
    *(uint4*)&Bl[srow][scol]     = *(const uint4*)(bp);
    *(uint4*)&Bl[srow][scol + 8] = *(const uint4*)(bp + 8);
    __syncthreads();
    bf16x8 af[4], bfr[4];
#pragma unroll
    for (int i = 0; i < 4; ++i) af[i]  = *(const bf16x8*)&Al[wr * 64 + i * 16 + fr][fq * 8];
#pragma unroll
    for (int j = 0; j < 4; ++j) bfr[j] = *(const bf16x8*)&Bl[wc * 64 + j * 16 + fr][fq * 8];
#pragma unroll
    for (int i = 0; i < 4; ++i)
#pragma unroll
      for (int j = 0; j < 4; ++j)
        acc[i][j] = __builtin_amdgcn_mfma_f32_16x16x32_bf16(af[i], bfr[j], acc[i][j], 0, 0, 0);
    __syncthreads();
  }

  const int rowb = by * 128 + wr * 64 + fq * 4;
  const int colb = bx * 128 + wc * 64 + fr;
#pragma unroll
  for (int j = 0; j < 4; ++j) {
    const int colg = colb + j * 16;
    const float bb = bias ? bias[colg] : 0.f;
#pragma unroll
    for (int i = 0; i < 4; ++i) {
      const int rowg = rowb + i * 16;
      if (OM == 0) {
        float* C = (float*)Cv;
#pragma unroll
        for (int r = 0; r < 4; ++r) {
          float o = acc[i][j][r] + bb;
          if (RELU) o = fmaxf(o, 0.f);
          C[(long)bz * sC + (long)(rowg + r) * ldC + colg] = o;
        }
      } else if (OM == 1) {
        ushort* C = (ushort*)Cv;
#pragma unroll
        for (int r = 0; r < 4; ++r) {
          float o = acc[i][j][r] + bb;
          if (RELU) o = fmaxf(o, 0.f);
          C[(long)bz * sC + (long)(rowg + r) * ldC + colg] = f2bf(o);
        }
      } else if (OM == 2) {
        float* C = (float*)Cv;
        const long ct = ((long)(rowg >> 9) * H_ + colg) * S_ + (rowg & 511);
        float4 o;
        o.x = acc[i][j][0] + bb; o.y = acc[i][j][1] + bb;
        o.z = acc[i][j][2] + bb; o.w = acc[i][j][3] + bb;
        *(float4*)&C[ct] = o;
      } else {
        ushort* C = (ushort*)Cv;
        const long ct = ((long)(rowg >> 9) * H_ + colg) * S_ + (rowg & 511);
        ushort4 o;
        o.x = f2bf(acc[i][j][0] + bb); o.y = f2bf(acc[i][j][1] + bb);
        o.z = f2bf(acc[i][j][2] + bb); o.w = f2bf(acc[i][j][3] + bb);
        *(ushort4*)&C[ct] = o;
      }
    }
  }
}

// ---------------- attention softmax: fp32 scores -> bf16 probs ----------------
__global__ __launch_bounds__(256) void attn_softmax(const float* __restrict__ att,
                                                    ushort* __restrict__ attb)
{
  __shared__ float red[4];
  const long row = blockIdx.x;
  const float* p = att + row * S_;
  const int t = threadIdx.x, lane = t & 63, wid = t >> 6;
  float v0 = p[t] * 0.0625f, v1 = p[t + 256] * 0.0625f;
  float m = wave_reduce_max(fmaxf(v0, v1));
  if (!lane) red[wid] = m;
  __syncthreads();
  const float bm = fmaxf(fmaxf(red[0], red[1]), fmaxf(red[2], red[3]));
  const float e0 = __expf(v0 - bm), e1 = __expf(v1 - bm);
  float s = wave_reduce_sum(e0 + e1);
  __syncthreads();
  if (!lane) red[wid] = s;
  __syncthreads();
  const float inv = __fdividef(1.f, red[0] + red[1] + red[2] + red[3]);
  ushort* q = attb + row * S_;
  q[t] = f2bf(e0 * inv); q[t + 256] = f2bf(e1 * inv);
}

// ---------------- residual + layernorm -> x (fp32) and xb (bf16) ----------------
__global__ __launch_bounds__(256) void ln_res(float* __restrict__ x, const float* __restrict__ y,
                                              const float* __restrict__ g, const float* __restrict__ b,
                                              ushort* __restrict__ xb)
{
  __shared__ float red[4];
  const long row = blockIdx.x;
  const int t = threadIdx.x, lane = t & 63, wid = t >> 6;
  float v = x[row * H_ + t] + y[row * H_ + t];
  float s = wave_reduce_sum(v);
  if (!lane) red[wid] = s;
  __syncthreads();
  const float mean = (red[0] + red[1] + red[2] + red[3]) * (1.f / H_);
  const float d = v - mean;
  float s2 = wave_reduce_sum(d * d);
  __syncthreads();
  if (!lane) red[wid] = s2;
  __syncthreads();
  const float var = (red[0] + red[1] + red[2] + red[3]) * (1.f / H_);
  const float o = d * rsqrtf(var + 1e-5f) * g[t] + b[t];
  x[row * H_ + t] = o;
  xb[row * H_ + t] = f2bf(o);
}

// ---------------- gather LSTM inputs from encb (bf16), step 0 zeroed ----------------
__global__ void gather_inputs(const int* __restrict__ tidx, const ushort* __restrict__ encb,
                              ushort* __restrict__ inpb)
{
  int idx = blockIdx.x * 256 + threadIdx.x;          // 1024*256
  int h = idx & 255, kb = idx >> 8;
  int b = kb & 63, k = kb >> 6;
  ushort v = 0;
  if (k > 0) {
    int s = tidx[b * K_ + k];
    v = encb[((long)b * S_ + s) * H_ + h];
  }
  inpb[idx] = v;
}

// ---------------- MFMA LSTM: one block/batch row, 8 waves, coalesced fragment loads ----------------
// Wave w owns gate cols [w*128, w*128+128) as 8 n-tiles of 16. W pre-permuted (whh_prep)
// so each fragment load is one contiguous 1KB wave transaction from L2.
__global__ __launch_bounds__(512) void lstm_mfma(const float* __restrict__ Xp,
                                                 const ushort* __restrict__ Wp,
                                                 const float* __restrict__ b_hh,
                                                 float* __restrict__ dec)
{
  __shared__ ushort hsb[H_];
  __shared__ float gates[H4_];
  const int b = blockIdx.x, tid = threadIdx.x;
  const int lane = tid & 63, wave = tid >> 6;        // 8 waves
  const int fq = lane >> 4;
  if (tid < 128) ((uint*)hsb)[tid] = 0;              // h = 0
  float c = 0.f;
  float bh0 = 0.f, bh1 = 0.f, bh2 = 0.f, bh3 = 0.f;
  if (tid < 256) {
    bh0 = b_hh[tid]; bh1 = b_hh[256 + tid]; bh2 = b_hh[512 + tid]; bh3 = b_hh[768 + tid];
  }
  __syncthreads();
  for (int step = 0; step < K_; ++step) {
    // A-fragments: h broadcast to all 16 rows (lanes read by their k-index)
    bf16x8 af[8];
#pragma unroll
    for (int kc = 0; kc < 8; ++kc)
      af[kc] = *(const bf16x8*)&hsb[kc * 32 + fq * 8];
#pragma unroll 2
    for (int nt = 0; nt < 8; ++nt) {
      const int ntg = wave * 8 + nt;
      const ushort* wp = Wp + ((long)(ntg * 8) * 64 + lane) * 8;
      f32x4 acc = {0.f, 0.f, 0.f, 0.f};
#pragma unroll
      for (int kc = 0; kc < 8; ++kc) {
        const bf16x8 bf = *(const bf16x8*)(wp + kc * 512);
        acc = __builtin_amdgcn_mfma_f32_16x16x32_bf16(af[kc], bf, acc, 0, 0, 0);
      }
      if (lane < 16) gates[ntg * 16 + lane] = acc[0];   // row 0 copy
    }
    __syncthreads();
    if (tid < 256) {
      const int j = tid;
      const long xrow = ((long)step * B_ + b) * H4_ + j;
      const float gi = gates[j]       + Xp[xrow]       + bh0;
      const float gf = gates[256 + j] + Xp[xrow + 256] + bh1;
      const float gg = gates[512 + j] + Xp[xrow + 512] + bh2;
      const float go = gates[768 + j] + Xp[xrow + 768] + bh3;
      c = sigmoid_fast(gf) * c + sigmoid_fast(gi) * tanh_fast(gg);
      const float h = sigmoid_fast(go) * tanh_fast(c);
      const long rw = ((long)step * B_ + b) * (2 * H_);
      dec[rw + j] = h;
      dec[rw + H_ + j] = c;
      hsb[j] = f2bf(h);
    }
    __syncthreads();
  }
}

// ---------------- glimpse: per-lane-s scores, softmax, weighted sum ----------------
__global__ __launch_bounds__(256) void glimpse_kernel(
    const float* __restrict__ decW1, const float* __restrict__ encW2T,
    const float* __restrict__ enc, const float* __restrict__ bias1,
    const float* __restrict__ V1, float* __restrict__ glim)
{
  __shared__ float dv[H_], vd[H_], sc[S_], red[4];
  const int bid = blockIdx.x;                // k*B + b
  const int b = bid & 63;
  const int t = threadIdx.x, lane = t & 63, wv = t >> 6;
  dv[t] = decW1[(long)bid * H_ + t] + bias1[t];
  vd[t] = V1[t];
  __syncthreads();
  const float* ebase = encW2T + (long)b * H_ * S_;
  float a0 = 0.f, a1 = 0.f;
#pragma unroll 4
  for (int h = 0; h < H_; ++h) {
    const float d = dv[h], w = vd[h];
    const float* r = ebase + (long)h * S_;
    a0 += tanh_fast(d + r[t]) * w;
    a1 += tanh_fast(d + r[t + 256]) * w;
  }
  float m = wave_reduce_max(fmaxf(a0, a1));
  if (!lane) red[wv] = m;
  __syncthreads();
  const float bm = fmaxf(fmaxf(red[0], red[1]), fmaxf(red[2], red[3]));
  const float e0 = __expf(a0 - bm), e1 = __expf(a1 - bm);
  float ssum = wave_reduce_sum(e0 + e1);
  __syncthreads();
  if (!lane) red[wv] = ssum;
  __syncthreads();
  const float inv = __fdividef(1.f, red[0] + red[1] + red[2] + red[3]);
  sc[t] = e0 * inv; sc[t + 256] = e1 * inv;
  __syncthreads();
  float acc = 0.f;
  const float* eb = enc + (long)b * S_ * H_ + t;
#pragma unroll 4
  for (int s = 0; s < S_; ++s) acc += sc[s] * eb[(long)s * H_];
  glim[(long)bid * H_ + t] = acc;
}

// ---------------- gcat = [dec | glim] -> bf16 ----------------
__global__ void concat_gcat(const float* __restrict__ dec, const float* __restrict__ glim,
                            ushort* __restrict__ gcatb)
{
  int idx = blockIdx.x * 256 + threadIdx.x;   // 1024*768
  int j = idx % 768, row = idx / 768;
  float v = (j < 512) ? dec[(long)row * 512 + j] : glim[(long)row * 256 + (j - 512)];
  gcatb[idx] = f2bf(v);
}

// ---------------- pointer logits -> out[b,k,s] ----------------
__global__ __launch_bounds__(256) void pointer_kernel(
    const float* __restrict__ gW3, const float* __restrict__ encW4T,
    const float* __restrict__ bias2, const float* __restrict__ V2,
    float* __restrict__ out)
{
  __shared__ float dv[H_], vd[H_];
  const int bid = blockIdx.x;                // k*B + b
  const int b = bid & 63, k = bid >> 6;
  const int t = threadIdx.x;
  dv[t] = gW3[(long)bid * H_ + t] + bias2[t];
  vd[t] = V2[t];
  __syncthreads();
  const float* ebase = encW4T + (long)b * H_ * S_;
  float a0 = 0.f, a1 = 0.f;
#pragma unroll 4
  for (int h = 0; h < H_; ++h) {
    const float d = dv[h], w = vd[h];
    const float* r = ebase + (long)h * S_;
    a0 += tanh_fast(d + r[t]) * w;
    a1 += tanh_fast(d + r[t + 256]) * w;
  }
  const long ro = ((long)b * K_ + k) * S_;
  out[ro + t] = a0;
  out[ro + 256 + t] = a1;
}

// ---------------- host ----------------
extern "C" void kernel_launch(void* const* d_in, const int* in_sizes, int n_in,
                              void* d_out, int out_size, void* d_ws, size_t ws_size,
                              hipStream_t stream)
{
  const int*   users = (const int*)d_in[0];
  const int*   cand  = (const int*)d_in[1];
  const int*   tidx  = (const int*)d_in[2];
  const float* eu    = (const float*)d_in[3];
  const float* ei    = (const float*)d_in[4];
  const float* Wq    = (const float*)d_in[5];
  const float* bq    = (const float*)d_in[6];
  const float* Wk    = (const float*)d_in[7];
  const float* bk    = (const float*)d_in[8];
  const float* Wv    = (const float*)d_in[9];
  const float* bv    = (const float*)d_in[10];
  const float* Wo    = (const float*)d_in[11];
  const float* bo    = (const float*)d_in[12];
  const float* ln1g  = (const float*)d_in[13];
  const float* ln1b  = (const float*)d_in[14];
  const float* Wf1   = (const float*)d_in[15];
  const float* bf1   = (const float*)d_in[16];
  const float* Wf2   = (const float*)d_in[17];
  const float* bf2   = (const float*)d_in[18];
  const float* ln2g  = (const float*)d_in[19];
  const float* ln2b  = (const float*)d_in[20];
  const float* W_ih  = (const float*)d_in[21];
  const float* W_hh  = (const float*)d_in[22];
  const float* b_ih  = (const float*)d_in[23];
  const float* b_hh  = (const float*)d_in[24];
  const float* W_D1  = (const float*)d_in[25];
  const float* W_D2  = (const float*)d_in[26];
  const float* bias1 = (const float*)d_in[27];
  const float* V_D1  = (const float*)d_in[28];
  const float* W_D3  = (const float*)d_in[29];
  const float* W_D4  = (const float*)d_in[30];
  const float* bias2 = (const float*)d_in[31];
  const float* V_D2  = (const float*)d_in[32];

  float* ws = (float*)d_ws;
  // arena (float-element offsets)
  float*  x      = ws;                               // fp32 8388608 (x -> enc)
  ushort* xb     = (ushort*)(ws + 8388608);          // bf16 (xb -> encb)
  ushort* qb     = (ushort*)(ws + 12582912);
  ushort* kb     = (ushort*)(ws + 16777216);
  ushort* vTb    = (ushort*)(ws + 20971520);         // [b][h][s] bf16
  ushort* aob    = (ushort*)(ws + 25165824);
  ushort* attb   = (ushort*)(ws + 29360128);         // 16x512x512 bf16 chunk
  float*  ych    = ws + 31457280;                    // 8192x256 fp32 chunk
  ushort* wts    = (ushort*)(ws + 33554432);         // bf16 weights arena
  float*  att    = ws + 34603008;                    // 16x512x512 fp32 chunk
  ushort* midb   = (ushort*)att;                     // alias: FFN phase (att dead)
  float*  sm     = ws + 38797312;                    // small arena
  float*  encW2T = ws + 12582912;                    // overlays qb+kb (dead)
  float*  encW4T = ws + 20971520;                    // overlays vTb+aob (dead)

  ushort* WqT  = wts;
  ushort* WkT  = WqT  + 65536;
  ushort* WvT  = WkT  + 65536;
  ushort* WoT  = WvT  + 65536;
  ushort* Wf1T = WoT  + 65536;
  ushort* Wf2T = Wf1T + 262144;
  ushort* WD1T = Wf2T + 262144;
  ushort* WD2T = WD1T + 131072;
  ushort* WD3T = WD2T + 65536;
  ushort* WD4T = WD3T + 196608;
  ushort* Wihb = WD4T + 65536;

  ushort* inpb   = (ushort*)sm;                      // 1024x256 bf16
  float*  Xp     = sm + 131072;                      // 1024x1024 fp32
  ushort* Wp     = (ushort*)(sm + 1179648);          // permuted W_hh bf16 (262144)
  float*  dec    = sm + 1441792;                     // 16x64x512 fp32
  ushort* decb   = (ushort*)(sm + 1966080);
  float*  decW1  = sm + 2228224;
  float*  glim   = sm + 2490368;
  ushort* gcatb  = (ushort*)(sm + 2752512);          // 1024x768 bf16
  float*  gcatW3 = sm + 3145728;

  float* out = (float*)d_out;
  const long SH = (long)S_ * H_;                     // 131072

  // 0. weight prep (transpose + cvt to bf16 [N,K])
  tcvt6<<<dim3(8,8,6), dim3(256), 0, stream>>>(Wq, WqT, Wk, WkT, Wv, WvT,
                                               Wo, WoT, W_D2, WD2T, W_D4, WD4T);
  tcvt<<<dim3(32,8),  dim3(256), 0, stream>>>(Wf1,  Wf1T, 256, 1024);
  tcvt<<<dim3(8,32),  dim3(256), 0, stream>>>(Wf2,  Wf2T, 1024, 256);
  tcvt<<<dim3(8,16),  dim3(256), 0, stream>>>(W_D1, WD1T, 512, 256);
  tcvt<<<dim3(8,24),  dim3(256), 0, stream>>>(W_D3, WD3T, 768, 256);
  cvtflat<<<dim3(1024), dim3(256), 0, stream>>>(W_ih, Wihb);   // already [N,K]
  whh_prep<<<dim3(1024), dim3(256), 0, stream>>>(W_hh, Wp);    // MFMA-fragment order

  // 1. gather
  gather_x<<<dim3(32768), dim3(256), 0, stream>>>(users, cand, eu, ei, x, xb);

  // 2. q,k (bf16 out), v (bf16 transposed out)
  gemm_bf16<1,false><<<dim3(2,256), dim3(256), 0, stream>>>(xb, WqT, bq, qb,  256, 256, 256, 256, 0,0,0);
  gemm_bf16<1,false><<<dim3(2,256), dim3(256), 0, stream>>>(xb, WkT, bk, kb,  256, 256, 256, 256, 0,0,0);
  gemm_bf16<3,false><<<dim3(2,256), dim3(256), 0, stream>>>(xb, WvT, bv, vTb, 256, 256, 256, 0,   0,0,0);

  // 3. attention: 4 chunks of 16 batches
  for (int c = 0; c < 4; ++c) {
    const long qo = (long)c * 16 * SH;
    gemm_bf16<0,false><<<dim3(4,4,16), dim3(256), 0, stream>>>(
        qb + qo, kb + qo, nullptr, att, 256, 256, 256, 512, SH, SH, (long)S_*S_);
    attn_softmax<<<dim3(16*S_), dim3(256), 0, stream>>>(att, attb);
    gemm_bf16<1,false><<<dim3(2,4,16), dim3(256), 0, stream>>>(
        attb, vTb + qo, nullptr, aob + qo, 512, 512, 512, 256, (long)S_*S_, SH, SH);
  }

  // 4. Wo + LN1, 4 row-chunks of 8192
  for (int c = 0; c < 4; ++c) {
    const long off = (long)c * 8192 * H_;
    gemm_bf16<0,false><<<dim3(2,64), dim3(256), 0, stream>>>(aob + off, WoT, bo, ych, 256, 256, 256, 256, 0,0,0);
    ln_res<<<dim3(8192), dim3(256), 0, stream>>>(x + off, ych, ln1g, ln1b, xb + off);
  }

  // 5. FFN, 4 row-chunks of 8192 (mid bf16 in att slot)
  for (int c = 0; c < 4; ++c) {
    const long off = (long)c * 8192 * H_;
    gemm_bf16<1,true ><<<dim3(8,64), dim3(256), 0, stream>>>(xb + off, Wf1T, bf1, midb, 256, 256, 256, 1024, 0,0,0);
    gemm_bf16<0,false><<<dim3(2,64), dim3(256), 0, stream>>>(midb, Wf2T, bf2, ych, 1024, 1024, 1024, 256, 0,0,0);
    ln_res<<<dim3(8192), dim3(256), 0, stream>>>(x + off, ych, ln2g, ln2b, xb + off);
  }
  // x = enc (fp32), xb = encb (bf16)

  // 6. enc projections, emitted pre-transposed [b][h][s] fp32
  gemm_bf16<2,false><<<dim3(2,256), dim3(256), 0, stream>>>(xb, WD2T, nullptr, encW2T, 256, 256, 256, 0, 0,0,0);
  gemm_bf16<2,false><<<dim3(2,256), dim3(256), 0, stream>>>(xb, WD4T, nullptr, encW4T, 256, 256, 256, 0, 0,0,0);

  // 7. LSTM
  gather_inputs<<<dim3(1024), dim3(256), 0, stream>>>(tidx, xb, inpb);
  gemm_bf16<0,false><<<dim3(8,8), dim3(256), 0, stream>>>(inpb, Wihb, b_ih, Xp, 256, 256, 256, 1024, 0,0,0);
  lstm_mfma<<<dim3(B_), dim3(512), 0, stream>>>(Xp, Wp, b_hh, dec);

  // 8. glimpse
  cvtflat<<<dim3(2048), dim3(256), 0, stream>>>(dec, decb);
  gemm_bf16<0,false><<<dim3(2,8), dim3(256), 0, stream>>>(decb, WD1T, nullptr, decW1, 512, 512, 512, 256, 0,0,0);
  glimpse_kernel<<<dim3(K_*B_), dim3(256), 0, stream>>>(decW1, encW2T, x, bias1, V_D1, glim);

  // 9. pointer
  concat_gcat<<<dim3(3072), dim3(256), 0, stream>>>(dec, glim, gcatb);
  gemm_bf16<0,false><<<dim3(2,8), dim3(256), 0, stream>>>(gcatb, WD3T, nullptr, gcatW3, 768, 768, 768, 256, 0,0,0);
  pointer_kernel<<<dim3(K_*B_), dim3(256), 0, stream>>>(gcatW3, encW4T, bias2, V_D2, out);
}